// Round 5
// baseline (445.551 us; speedup 1.0000x reference)
//
#include <hip/hip_runtime.h>

typedef __bf16 bf16;
typedef __bf16 bf16x8 __attribute__((ext_vector_type(8)));
typedef short short8 __attribute__((ext_vector_type(8)));
typedef float f32x4 __attribute__((ext_vector_type(4)));

// Runtime-dual input loader: bf=1 -> buffer holds bf16, else f32.
__device__ __forceinline__ float ldf(const void* p, size_t i, int bf) {
  if (bf) {
    unsigned int u = ((const unsigned short*)p)[i];
    union { unsigned int ui; float f; } c;
    c.ui = u << 16;
    return c.f;
  }
  return ((const float*)p)[i];
}

// XOR swizzle for bf16 LDS tiles read as ds_read_b128 (16B chunks).
__device__ __forceinline__ int sw8(int r) { return ((r ^ (r >> 2)) & 7) << 3; }

// pack two floats as bf16 pair into u32 (low = a, high = b)
__device__ __forceinline__ unsigned pk2(float a, float b) {
  union { bf16 h[2]; unsigned u; } c;
  c.h[0] = (bf16)a; c.h[1] = (bf16)b;
  return c.u;
}

// ---------------------------------------------------------------------------
// Dtype detector (unchanged).
// ---------------------------------------------------------------------------
__global__ void k_detect(const void* x, int* flag)
{
  int tid = threadIdx.x;  // 64 threads
  int cnt = 0;
  for (int j = 0; j < 4; j++) {
    int i = (tid * 4 + j) * 2;
    unsigned int u = ((const unsigned short*)x)[i];
    union { unsigned int ui; float f; } c;
    c.ui = u << 16;
    float a = fabsf(c.f);
    if (a >= 1e-4f && a <= 100.f) cnt++;
  }
  for (int m = 1; m < 64; m <<= 1) cnt += __shfl_xor(cnt, m);
  if (tid == 0) *flag = (cnt > 128) ? 1 : 0;
}

// ---------------------------------------------------------------------------
// ck/cv = context @ Wck/Wcv + bias   (4096 rows x 64) -> f32 internal
// ---------------------------------------------------------------------------
__global__ __launch_bounds__(256)
void k_ctx(const int* flagp, const void* ctx, const void* Wck, const void* bck,
           const void* Wcv, const void* bcv, float* __restrict__ ck,
           float* __restrict__ cv)
{
  const int bf = *flagp;
  int rid = blockIdx.x * 4 + (threadIdx.x >> 6);
  int dp = threadIdx.x & 63;
  float a1 = 0.f, a2 = 0.f;
  for (int e = 0; e < 64; e++) {
    float c = ldf(ctx, (size_t)rid * 64 + e, bf);
    a1 += c * ldf(Wck, e * 64 + dp, bf);
    a2 += c * ldf(Wcv, e * 64 + dp, bf);
  }
  ck[rid * 64 + dp] = a1 + ldf(bck, dp, bf);
  cv[rid * 64 + dp] = a2 + ldf(bcv, dp, bf);
}

// ---------------------------------------------------------------------------
// ckq[s][din] = Wcq-row(din) . ck[s] ; cqb[s] = bcq . ck[s]
// Gk[h*64+j][din] = Wk-row(din) . G[h][j] ; gb[h*64+j] = G[h][j] . bk
// ---------------------------------------------------------------------------
__global__ __launch_bounds__(256)
void k_fold(const int* flagp, const float* __restrict__ ck, const void* Wcq,
            const void* bcq, const void* qg, const void* Wk, const void* bk,
            float* __restrict__ ckq, float* __restrict__ cqb,
            float* __restrict__ Gk, float* __restrict__ gb)
{
  const int bf = *flagp;
  int bid = blockIdx.x, tid = threadIdx.x;
  if (bid < 1024) {
    int rid = bid * 4 + (tid >> 6), dp = tid & 63;
    const float* c = ck + (size_t)rid * 64;
    float a = 0.f;
    for (int o = 0; o < 64; o++) a += c[o] * ldf(Wcq, dp * 64 + o, bf);
    ckq[rid * 64 + dp] = a;
    if (dp == 0) {
      float s = 0.f;
      for (int o = 0; o < 64; o++) s += ldf(bcq, o, bf) * c[o];
      cqb[rid] = s;
    }
  } else {
    int i = (bid - 1024) * 256 + tid;    // [0, 32768)
    int row = i >> 6, dIn = i & 63;
    float s = 0.f;
    for (int d = 0; d < 64; d++)
      s += ldf(qg, (size_t)row * 64 + d, bf) * ldf(Wk, dIn * 64 + d, bf);
    Gk[i] = s;
    if (dIn == 0) {
      float t = 0.f;
      for (int d = 0; d < 64; d++)
        t += ldf(qg, (size_t)row * 64 + d, bf) * ldf(bk, d, bf);
      gb[row] = t;
    }
  }
}

// ---------------------------------------------------------------------------
// Attn image prep: build bf16 pre-swizzled LDS images in global memory.
//   bid 0..15 : ckq f32 -> g_ckqb[bh] ([s][64] swz)
//   bid 16..31: cv  f32 -> g_cvtb[bh] (transposed [d][256] swz)
//   bid 32    : Gk  f32 -> g_gkb[h]   ([j][64] swz)
// ---------------------------------------------------------------------------
__global__ __launch_bounds__(256)
void k_prep(const float* __restrict__ ckq, const float* __restrict__ cv,
            const float* __restrict__ Gk, bf16* __restrict__ g_ckqb,
            bf16* __restrict__ g_cvtb, bf16* __restrict__ g_gkb)
{
  const int bid = blockIdx.x, tid = threadIdx.x;
  if (bid < 16) {
    const float* src = ckq + (size_t)bid * 16384;
    bf16* dst = g_ckqb + (size_t)bid * 16384;
    for (int e = tid; e < 16384; e += 256) {
      int r = e >> 6, c = e & 63;
      dst[r * 64 + (c ^ sw8(r))] = (bf16)src[e];
    }
  } else if (bid < 32) {
    int bh = bid - 16;
    const float* src = cv + (size_t)bh * 16384;
    bf16* dst = g_cvtb + (size_t)bh * 16384;
    for (int e = tid; e < 16384; e += 256) {
      int d = e >> 8, s = e & 255;
      dst[d * 256 + (s ^ sw8(d))] = (bf16)src[s * 64 + d];
    }
  } else {
    for (int e = tid; e < 32768; e += 256) {
      int hh = e >> 12, r = (e >> 6) & 63, c = e & 63;
      g_gkb[hh * 4096 + r * 64 + (c ^ sw8(r))] = (bf16)Gk[e];
    }
  }
}

// ---------------------------------------------------------------------------
// Weight prep: WT[n][k] = (bf16)W[k][n] for Wp (blocks 0..63) and Wo (64..127).
// ---------------------------------------------------------------------------
__global__ __launch_bounds__(256)
void k_wtr(const int* flagp, const void* Wp, const void* Wo,
           bf16* __restrict__ WpT, bf16* __restrict__ WoT)
{
  const int bf = *flagp;
  const int bid = blockIdx.x, tid = threadIdx.x;
  const void* W = (bid < 64) ? Wp : Wo;
  bf16* WT = (bid < 64) ? WpT : WoT;
  const int tb = bid & 63, kb = tb & 7, nb = tb >> 3;
  __shared__ float t[64][65];
  for (int e = tid; e < 4096; e += 256) {
    int k = e >> 6, n = e & 63;
    t[k][n] = ldf(W, (size_t)(kb * 64 + k) * 512 + nb * 64 + n, bf);
  }
  __syncthreads();
  for (int e = tid; e < 4096; e += 256) {
    int n = e >> 6, k = e & 63;
    WT[(size_t)(nb * 64 + n) * 512 + kb * 64 + k] = (bf16)t[k][n];
  }
}

// ---------------------------------------------------------------------------
// MFMA GEMM: out(Mx512) = A(Mx512) @ W(512x512) + bias (unchanged from r4).
// ---------------------------------------------------------------------------
__global__ __launch_bounds__(256)
void k_gemm_mfma(const int* flagp, const void* A, const int amode,
                 const bf16* __restrict__ WT, const void* bias, void* out,
                 const int omode)
{
  __shared__ __attribute__((aligned(16))) bf16 AsB[2][128 * 64];
  __shared__ __attribute__((aligned(16))) bf16 BsB[2][128 * 64];

  const int bf = *flagp;
  const int abf = (amode == 1) || bf;
  const int tid = threadIdx.x;
  const int srow = tid >> 3, schk = tid & 7;

  const int orig = blockIdx.y * 4 + blockIdx.x;
  const int nid = (orig & 7) * 128 + (orig >> 3);
  const int m0 = (nid >> 2) * 128, n0 = (nid & 3) * 128;

  const int lane = tid & 63, wid = tid >> 6;
  const int lo = lane & 15, hi = lane >> 4;
  const int wm = (wid >> 1) * 64, wn = (wid & 1) * 64;

  f32x4 rf[4][2];
  bf16x8 rb[4];
  bf16x8 rw[4];

  auto ldreg = [&](int kt) {
    const int koff = kt * 64 + schk * 8;
#pragma unroll
    for (int i = 0; i < 4; i++) {
      const int row = i * 32 + srow;
      if (abf) {
        rb[i] = *(const bf16x8*)((const bf16*)A + (size_t)(m0 + row) * 512 + koff);
      } else {
        const float* ap = (const float*)A + (size_t)(m0 + row) * 512 + koff;
        rf[i][0] = *(const f32x4*)ap;
        rf[i][1] = *(const f32x4*)(ap + 4);
      }
      rw[i] = *(const bf16x8*)(WT + (size_t)(n0 + row) * 512 + koff);
    }
  };
  auto stlds = [&](bf16* As, bf16* Bs) {
    const int c = schk * 8;
#pragma unroll
    for (int i = 0; i < 4; i++) {
      const int row = i * 32 + srow;
      bf16x8 v;
      if (abf) {
        v = rb[i];
      } else {
#pragma unroll
        for (int j = 0; j < 4; j++) {
          v[j] = (bf16)rf[i][0][j];
          v[4 + j] = (bf16)rf[i][1][j];
        }
      }
      *(bf16x8*)&As[row * 64 + (c ^ sw8(row))] = v;
      *(bf16x8*)&Bs[row * 64 + (c ^ sw8(row))] = rw[i];
    }
  };

  f32x4 acc[4][4];
#pragma unroll
  for (int mt = 0; mt < 4; mt++)
#pragma unroll
    for (int nt = 0; nt < 4; nt++) acc[mt][nt] = f32x4{0.f, 0.f, 0.f, 0.f};

  ldreg(0);
  stlds(AsB[0], BsB[0]);
  __syncthreads();

  int cur = 0;
  for (int kt = 0; kt < 8; kt++) {
    if (kt < 7) ldreg(kt + 1);
    const bf16* Asc = AsB[cur];
    const bf16* Bsc = BsB[cur];
#pragma unroll
    for (int ks = 0; ks < 2; ks++) {
      short8 af[4], bq[4];
#pragma unroll
      for (int mt = 0; mt < 4; mt++) {
        int r = wm + mt * 16 + lo;
        af[mt] = *(const short8*)&Asc[r * 64 + ((ks * 32 + hi * 8) ^ sw8(r))];
      }
#pragma unroll
      for (int nt = 0; nt < 4; nt++) {
        int r = wn + nt * 16 + lo;
        bq[nt] = *(const short8*)&Bsc[r * 64 + ((ks * 32 + hi * 8) ^ sw8(r))];
      }
#pragma unroll
      for (int mt = 0; mt < 4; mt++)
#pragma unroll
        for (int nt = 0; nt < 4; nt++)
          acc[mt][nt] = __builtin_amdgcn_mfma_f32_16x16x32_bf16(
              af[mt], bq[nt], acc[mt][nt], 0, 0, 0);
    }
    if (kt < 7) stlds(AsB[cur ^ 1], BsB[cur ^ 1]);
    __syncthreads();
    cur ^= 1;
  }

#pragma unroll
  for (int nt = 0; nt < 4; nt++) {
    const int col = n0 + wn + nt * 16 + lo;
    const float bj = ldf(bias, col, bf);
#pragma unroll
    for (int mt = 0; mt < 4; mt++)
#pragma unroll
      for (int r = 0; r < 4; r++) {
        const int rowg = m0 + wm + mt * 16 + hi * 4 + r;
        const float v = acc[mt][nt][r] + bj;
        const size_t oi = (size_t)rowg * 512 + col;
        if (omode == 0 || bf) ((bf16*)out)[oi] = (bf16)v;
        else                  ((float*)out)[oi] = v;
      }
  }
}

// ---------------------------------------------------------------------------
// Stage B (MFMA) (unchanged from r4).
// ---------------------------------------------------------------------------
__global__ __launch_bounds__(256, 2)
void k_stageB(const float* __restrict__ Gk, const float* __restrict__ gb,
              const bf16* __restrict__ xm, float* __restrict__ zpart,
              float* __restrict__ lpart)
{
  __shared__ __attribute__((aligned(16))) char smem[8192 + 65536 + 1024];
  bf16* GkB = (bf16*)smem;
  const int tid = threadIdx.x;
  const int bh = blockIdx.y, b = bh >> 3, h = bh & 7;
  const int split = blockIdx.x;

#pragma unroll
  for (int it = 0; it < 2; it++) {
    int idx = tid + it * 256;
    int r = idx >> 3, c0 = (idx & 7) * 8;
    const float* g = Gk + (size_t)(h * 64 + r) * 64 + c0;
    bf16x8 v;
#pragma unroll
    for (int t = 0; t < 8; t++) v[t] = (bf16)g[t];
    *(bf16x8*)&GkB[r * 64 + (c0 ^ sw8(r))] = v;
  }
  __syncthreads();

  const int wid = tid >> 6, lane = tid & 63;
  const int lo = lane & 15, hi = lane >> 4;
  bf16*  Ew  = (bf16*)(smem + 8192 + wid * 16384);
  short* Xts = (short*)(smem + 8192 + wid * 16384 + 8192);

  short8 gk[4][2];
#pragma unroll
  for (int jt = 0; jt < 4; jt++)
#pragma unroll
    for (int ks = 0; ks < 2; ks++) {
      int r = jt * 16 + lo;
      gk[jt][ks] = *(const short8*)&GkB[r * 64 + ((ks * 32 + hi * 8) ^ sw8(r))];
    }
  float gbl[4][4];
#pragma unroll
  for (int jt = 0; jt < 4; jt++)
#pragma unroll
    for (int r = 0; r < 4; r++)
      gbl[jt][r] = gb[h * 64 + jt * 16 + hi * 4 + r];

  f32x4 zacc[4][4];
  float lacc[4][4];
#pragma unroll
  for (int jt = 0; jt < 4; jt++)
#pragma unroll
    for (int q = 0; q < 4; q++) {
      zacc[jt][q] = f32x4{0.f, 0.f, 0.f, 0.f};
      lacc[jt][q] = 0.f;
    }

  const int tokbase = split * 512 + wid * 128;
  for (int t = 0; t < 4; t++) {
    const int t0 = tokbase + t * 32;
    short8 bx[2][2];
#pragma unroll
    for (int tt = 0; tt < 2; tt++)
#pragma unroll
      for (int ks = 0; ks < 2; ks++)
        bx[tt][ks] = *(const short8*)(xm +
            (size_t)(b * 16384 + t0 + tt * 16 + lo) * 512 + h * 64 +
            ks * 32 + hi * 8);
#pragma unroll
    for (int tt = 0; tt < 2; tt++)
#pragma unroll
      for (int ks = 0; ks < 2; ks++)
#pragma unroll
        for (int e = 0; e < 8; e++) {
          int d = ks * 32 + hi * 8 + e;
          int tok = tt * 16 + lo;
          Xts[d * 64 + (tok ^ sw8(d))] = bx[tt][ks][e];
        }
    f32x4 s[4][2];
#pragma unroll
    for (int jt = 0; jt < 4; jt++)
#pragma unroll
      for (int tt = 0; tt < 2; tt++) s[jt][tt] = f32x4{0.f, 0.f, 0.f, 0.f};
#pragma unroll
    for (int ks = 0; ks < 2; ks++)
#pragma unroll
      for (int jt = 0; jt < 4; jt++)
#pragma unroll
        for (int tt = 0; tt < 2; tt++)
          s[jt][tt] = __builtin_amdgcn_mfma_f32_16x16x32_bf16(
              gk[jt][ks], bx[tt][ks], s[jt][tt], 0, 0, 0);
#pragma unroll
    for (int jt = 0; jt < 4; jt++)
#pragma unroll
      for (int tt = 0; tt < 2; tt++)
#pragma unroll
        for (int r = 0; r < 4; r++) {
          int j = jt * 16 + hi * 4 + r;
          int tok = tt * 16 + lo;
          float e = __expf(s[jt][tt][r] + gbl[jt][r]);
          lacc[jt][r] += e;
          Ew[j * 64 + (tok ^ sw8(j))] = (bf16)e;
        }
    short8 ea[4], xb[4];
#pragma unroll
    for (int jt = 0; jt < 4; jt++) {
      int r = jt * 16 + lo;
      ea[jt] = *(const short8*)&Ew[r * 64 + ((hi * 8) ^ sw8(r))];
    }
#pragma unroll
    for (int dt = 0; dt < 4; dt++) {
      int d = dt * 16 + lo;
      xb[dt] = *(const short8*)(Xts + d * 64 + ((hi * 8) ^ sw8(d)));
    }
#pragma unroll
    for (int jt = 0; jt < 4; jt++)
#pragma unroll
      for (int dt = 0; dt < 4; dt++)
        zacc[jt][dt] = __builtin_amdgcn_mfma_f32_16x16x32_bf16(
            ea[jt], xb[dt], zacc[jt][dt], 0, 0, 0);
  }

  float* lred = (float*)(smem + 8192 + 65536);
#pragma unroll
  for (int jt = 0; jt < 4; jt++)
#pragma unroll
    for (int r = 0; r < 4; r++) {
      float v = lacc[jt][r];
      for (int m = 1; m < 16; m <<= 1) v += __shfl_xor(v, m);
      if (lo == 0) lred[wid * 64 + jt * 16 + hi * 4 + r] = v;
    }
  __syncthreads();

  float* zred = (float*)(smem + 8192);
#pragma unroll
  for (int jt = 0; jt < 4; jt++)
#pragma unroll
    for (int dt = 0; dt < 4; dt++)
#pragma unroll
      for (int r = 0; r < 4; r++)
        zred[wid * 4096 + (jt * 16 + hi * 4 + r) * 64 + dt * 16 + lo] =
            zacc[jt][dt][r];
  __syncthreads();

  const size_t pbase = ((size_t)bh * 32 + split) * 4096;
  for (int i = tid; i < 4096; i += 256)
    zpart[pbase + i] =
        zred[i] + zred[4096 + i] + zred[8192 + i] + zred[12288 + i];
  if (tid < 64)
    lpart[((size_t)bh * 32 + split) * 64 + tid] =
        lred[tid] + lred[64 + tid] + lred[128 + tid] + lred[192 + tid];
}

// z^T image (bf16, [d][j], swizzled) = (sum_split zpart / l_j) @ Wv + bv
__global__ __launch_bounds__(256)
void k_znorm(const int* flagp, const float* __restrict__ zpart,
             const float* __restrict__ lpart, const void* Wv, const void* bv,
             bf16* __restrict__ g_ztb)
{
  const int bf = *flagp;
  const int bh = blockIdx.x, tid = threadIdx.x;
  __shared__ float zsum[4096];
  __shared__ float lsum[64];
  for (int i = tid; i < 4096; i += 256) {
    float s = 0.f;
    for (int sp = 0; sp < 32; sp++)
      s += zpart[((size_t)bh * 32 + sp) * 4096 + i];
    zsum[i] = s;
  }
  if (tid < 64) {
    float s = 0.f;
    for (int sp = 0; sp < 32; sp++) s += lpart[((size_t)bh * 32 + sp) * 64 + tid];
    lsum[tid] = s;
  }
  __syncthreads();
  for (int i = tid; i < 4096; i += 256) {
    int j = i >> 6, d = i & 63;
    float inv = 1.f / lsum[j];
    float s = 0.f;
    for (int e = 0; e < 64; e++)
      s += zsum[j * 64 + e] * ldf(Wv, e * 64 + d, bf);
    g_ztb[(size_t)bh * 4096 + d * 64 + (j ^ sw8(d))] =
        (bf16)(s * inv + ldf(bv, d, bf));
  }
}

// ---------------------------------------------------------------------------
// Merged MFMA flash attention, swapped-QK + in-register P transpose.
// D_qk[ctx][tok]: lane(lo,hi) reg(ct,r) holds ctx=c0+ct*16+hi*4+r, tok=rt*16+lo.
// PV A-frag assembled via 8 shfl + 4 select per rt (mapping verified vs
// k_stageB's harness-passing swapped layout).
// ---------------------------------------------------------------------------
template <int NCH, int VSTR, int NB>
__device__ __forceinline__ void attn_part2(
    const bf16* __restrict__ Aq, const bf16* __restrict__ BvT,
    const float (&breg)[NB], const short8 (&ax)[2][2],
    int lo, int hi, f32x4 (&accO)[2][4], float (&ltok)[2])
{
#pragma unroll
  for (int ch = 0; ch < NCH; ch++) {
    const int c0 = ch * 32;
    f32x4 s[2][2];  // [ct][rt]
#pragma unroll
    for (int ct = 0; ct < 2; ct++)
#pragma unroll
      for (int rt = 0; rt < 2; rt++) s[ct][rt] = f32x4{0.f, 0.f, 0.f, 0.f};
#pragma unroll
    for (int ks = 0; ks < 2; ks++) {
      short8 aq[2];
#pragma unroll
      for (int ct = 0; ct < 2; ct++) {
        int n = c0 + ct * 16 + lo;
        aq[ct] = *(const short8*)(Aq + n * 64 + ((ks * 32 + hi * 8) ^ sw8(n)));
      }
#pragma unroll
      for (int ct = 0; ct < 2; ct++)
#pragma unroll
        for (int rt = 0; rt < 2; rt++)
          s[ct][rt] = __builtin_amdgcn_mfma_f32_16x16x32_bf16(
              aq[ct], ax[rt][ks], s[ct][rt], 0, 0, 0);
    }
    // bias + exp + pack (w[rt][ct][q] = bf16 pair of r-values)
    unsigned w[2][2][2];
#pragma unroll
    for (int ct = 0; ct < 2; ct++) {
      float b[4];
#pragma unroll
      for (int r = 0; r < 4; r++)
        b[r] = __shfl(breg[(c0 + ct * 16) >> 6],
                      ((c0 + ct * 16) & 63) + hi * 4 + r);
#pragma unroll
      for (int rt = 0; rt < 2; rt++) {
        float e0 = __expf(s[ct][rt][0] + b[0]);
        float e1 = __expf(s[ct][rt][1] + b[1]);
        float e2 = __expf(s[ct][rt][2] + b[2]);
        float e3 = __expf(s[ct][rt][3] + b[3]);
        ltok[rt] += e0 + e1 + e2 + e3;
        w[rt][ct][0] = pk2(e0, e1);
        w[rt][ct][1] = pk2(e2, e3);
      }
    }
    // exchange -> PV A-frag, then PV MFMA
#pragma unroll
    for (int rt = 0; rt < 2; rt++) {
      const int s0 = lo + 32 * (hi & 1);
      unsigned t00 = __shfl(w[rt][0][0], s0);
      unsigned t10 = __shfl(w[rt][1][0], s0);
      unsigned t01 = __shfl(w[rt][0][1], s0);
      unsigned t11 = __shfl(w[rt][1][1], s0);
      unsigned t20 = __shfl(w[rt][0][0], s0 + 16);
      unsigned t30 = __shfl(w[rt][1][0], s0 + 16);
      unsigned t21 = __shfl(w[rt][0][1], s0 + 16);
      unsigned t31 = __shfl(w[rt][1][1], s0 + 16);
      union { unsigned u[4]; short8 s8; } pa;
      const bool c1 = (hi >> 1) != 0;
      pa.u[0] = c1 ? t10 : t00;
      pa.u[1] = c1 ? t11 : t01;
      pa.u[2] = c1 ? t30 : t20;
      pa.u[3] = c1 ? t31 : t21;
#pragma unroll
      for (int dt = 0; dt < 4; dt++) {
        int d = dt * 16 + lo;
        short8 bv = *(const short8*)(BvT + d * VSTR + ((c0 + hi * 8) ^ sw8(d)));
        accO[rt][dt] = __builtin_amdgcn_mfma_f32_16x16x32_bf16(
            pa.s8, bv, accO[rt][dt], 0, 0, 0);
      }
    }
  }
}

__global__ __launch_bounds__(512, 4)
void k_attn(const int* flagp, const bf16* __restrict__ g_gkb,
            const bf16* __restrict__ g_ztb, const bf16* __restrict__ g_ckqb,
            const bf16* __restrict__ g_cvtb, const float* __restrict__ cqb,
            const float* __restrict__ gb, const bf16* __restrict__ xm,
            const void* smix, bf16* __restrict__ selfmid)
{
  __shared__ __attribute__((aligned(16))) bf16 S[40960];  // exactly 80 KiB
  bf16* GkB  = S;             // [64][64]
  bf16* zTB  = S + 4096;      // [64][64]
  bf16* ckqB = S + 8192;      // [256][64]
  bf16* cvTB = S + 24576;     // [64][256]

  const int tid = threadIdx.x;
  const int bh = blockIdx.y, b = bh >> 3, h = bh & 7;
  const int lane = tid & 63;

  // coalesced image staging
  {
    int i = tid;  // 512 chunks of 8 for GkB/zTB
    *(bf16x8*)&GkB[i * 8] = *(const bf16x8*)&g_gkb[(size_t)h * 4096 + i * 8];
    *(bf16x8*)&zTB[i * 8] = *(const bf16x8*)&g_ztb[(size_t)bh * 4096 + i * 8];
#pragma unroll
    for (int it = 0; it < 4; it++) {
      int j = tid + it * 512;
      *(bf16x8*)&ckqB[j * 8] =
          *(const bf16x8*)&g_ckqb[(size_t)bh * 16384 + j * 8];
      *(bf16x8*)&cvTB[j * 8] =
          *(const bf16x8*)&g_cvtb[(size_t)bh * 16384 + j * 8];
    }
  }
  float creg[4], greg[1];
#pragma unroll
  for (int q = 0; q < 4; q++) creg[q] = cqb[bh * 256 + q * 64 + lane];
  greg[0] = gb[h * 64 + lane];
  __syncthreads();

  const int wid = tid >> 6;
  const int lo = lane & 15, hi = lane >> 4;
  const int m0 = blockIdx.x * 256 + wid * 32;

  short8 ax[2][2];
#pragma unroll
  for (int rt = 0; rt < 2; rt++)
#pragma unroll
    for (int ks = 0; ks < 2; ks++)
      ax[rt][ks] = *(const short8*)(xm +
          (size_t)(b * 16384 + m0 + rt * 16 + lo) * 512 + h * 64 +
          ks * 32 + hi * 8);

  f32x4 accS[2][4], accC[2][4];
  float l1[2] = {0.f, 0.f}, l2[2] = {0.f, 0.f};
#pragma unroll
  for (int rt = 0; rt < 2; rt++)
#pragma unroll
    for (int dt = 0; dt < 4; dt++) {
      accS[rt][dt] = f32x4{0.f, 0.f, 0.f, 0.f};
      accC[rt][dt] = f32x4{0.f, 0.f, 0.f, 0.f};
    }

  attn_part2<2, 64, 1>(GkB, zTB, greg, ax, lo, hi, accS, l1);     // self
  attn_part2<8, 256, 4>(ckqB, cvTB, creg, ax, lo, hi, accC, l2);  // cross

  // token-row softmax denominators (lane-local, reduce over hi groups)
#pragma unroll
  for (int rt = 0; rt < 2; rt++) {
    float a = l1[rt], c = l2[rt];
    a += __shfl_xor(a, 16); a += __shfl_xor(a, 32);
    c += __shfl_xor(c, 16); c += __shfl_xor(c, 32);
    l1[rt] = 1.f / a;
    l2[rt] = 1.f / c;
  }

  const int bf = *flagp;
  const float wmix = 1.f / (1.f + __expf(-ldf(smix, 0, bf)));
#pragma unroll
  for (int rt = 0; rt < 2; rt++)
#pragma unroll
    for (int r = 0; r < 4; r++) {
      const float invS = __shfl(l1[rt], hi * 4 + r);
      const float invC = __shfl(l2[rt], hi * 4 + r);
      int row = m0 + rt * 16 + hi * 4 + r;
      size_t off = (size_t)(b * 16384 + row) * 512 + h * 64;
#pragma unroll
      for (int dt = 0; dt < 4; dt++) {
        float vS = accS[rt][dt][r] * invS;
        float vC = accC[rt][dt][r] * invC;
        selfmid[off + dt * 16 + lo] = (bf16)(wmix * vS + (1.f - wmix) * vC);
      }
    }
}

// ---------------------------------------------------------------------------
extern "C" void kernel_launch(void* const* d_in, const int* in_sizes, int n_in,
                              void* d_out, int out_size, void* d_ws, size_t ws_size,
                              hipStream_t stream)
{
  const void* x    = d_in[0];
  const void* ctx  = d_in[1];
  const void* qg   = d_in[2];
  const void* Wp   = d_in[3];  const void* bp  = d_in[4];
  const void* Wk   = d_in[5];  const void* bk  = d_in[6];
  const void* Wv   = d_in[7];  const void* bv  = d_in[8];
  const void* Wcq  = d_in[9];  const void* bcq = d_in[10];
  const void* Wck  = d_in[11]; const void* bck = d_in[12];
  const void* Wcv  = d_in[13]; const void* bcv = d_in[14];
  const void* smix = d_in[15];
  const void* Wo   = d_in[16]; const void* bo  = d_in[17];

  char* ws = (char*)d_ws;
  int*   flag    = (int*)(ws);                   // 256 B reserved
  float* ck      = (float*)(ws + 256);           // 1,048,576 (dead after k_fold)
  float* cv      = (float*)(ws + 1048832);       // 1,048,576 (f32, -> k_prep)
  float* ckq     = (float*)(ws + 2097408);       // 1,048,576 (f32, -> k_prep)
  float* cqb     = (float*)(ws + 3145984);       // 16,384
  float* Gk      = (float*)(ws + 3162368);       // 131,072
  float* gb      = (float*)(ws + 3293440);       // 2,048 (ends 3295488)
  // bf16 pre-swizzled attn images (old lbuf/zpre gap + old z region):
  bf16*  g_cvtb  = (bf16*)(ws + 3295744);        // 512 KiB
  bf16*  g_ckqb  = (bf16*)(ws + 3820032);        // 512 KiB (ends 4344320)
  bf16*  g_gkb   = (bf16*)(ws + 4348160);        // 64 KiB
  bf16*  g_ztb   = (bf16*)(ws + 4413696);        // 128 KiB (ends 4541952)
  bf16*  xm      = (bf16*)(ws + 5396736);        // 33,554,432 (bf16)
  bf16*  selfmid = (bf16*)(ws + 38951168);       // 33,554,432 (bf16)
  // WpT/WoT reuse the ck region (dead after k_fold)
  bf16*  WpT     = (bf16*)(ws + 256);
  bf16*  WoT     = (bf16*)(ws + 256 + 524288);
  // zpart/lpart park in the selfmid region (dead until k_attn)
  float* zpart   = (float*)(ws + 38951168);
  float* lpart   = (float*)(ws + 38951168 + 8388608);

  k_detect<<<1, 64, 0, stream>>>(x, flag);

  k_ctx<<<1024, 256, 0, stream>>>(flag, ctx, Wck, bck, Wcv, bcv, ck, cv);
  k_fold<<<1152, 256, 0, stream>>>(flag, ck, Wcq, bcq, qg, Wk, bk,
                                   ckq, cqb, Gk, gb);

  // bf16 pre-swizzled attn images + weight transposes
  k_prep<<<33, 256, 0, stream>>>(ckq, cv, Gk, g_ckqb, g_cvtb, g_gkb);
  k_wtr<<<128, 256, 0, stream>>>(flag, Wp, Wo, WpT, WoT);

  // x_mid (flat (b,n,h*64+d), bf16) = x @ Wp + bp   [MFMA]
  k_gemm_mfma<<<dim3(4, 256), 256, 0, stream>>>(flag, x, 0, WpT, bp, xm, 0);

  // z partials via MFMA split-K over tokens
  k_stageB<<<dim3(32, 16), 256, 0, stream>>>(Gk, gb, xm, zpart, lpart);
  k_znorm<<<16, 256, 0, stream>>>(flag, zpart, lpart, Wv, bv, g_ztb);

  // merged MFMA self+cross attention + sigmoid mix -> selfmid
  k_attn<<<dim3(64, 16), 512, 0, stream>>>(flag, g_gkb, g_ztb, g_ckqb, g_cvtb,
                                           cqb, (const float*)gb, xm, smix,
                                           selfmid);

  // out = selfmid @ Wo + bo  (output dtype chosen by flag)   [MFMA]
  k_gemm_mfma<<<dim3(4, 256), 256, 0, stream>>>(flag, selfmid, 1, WoT, bo,
                                                d_out, 1);
}

// Round 6
// 373.975 us; speedup vs baseline: 1.1914x; 1.1914x over previous
//
#include <hip/hip_runtime.h>

typedef __bf16 bf16;
typedef __bf16 bf16x8 __attribute__((ext_vector_type(8)));
typedef short short8 __attribute__((ext_vector_type(8)));
typedef float f32x4 __attribute__((ext_vector_type(4)));

// Runtime-dual input loader: bf=1 -> buffer holds bf16, else f32.
__device__ __forceinline__ float ldf(const void* p, size_t i, int bf) {
  if (bf) {
    unsigned int u = ((const unsigned short*)p)[i];
    union { unsigned int ui; float f; } c;
    c.ui = u << 16;
    return c.f;
  }
  return ((const float*)p)[i];
}

// XOR swizzle for bf16 LDS tiles read as ds_read_b128 (16B chunks).
__device__ __forceinline__ int sw8(int r) { return ((r ^ (r >> 2)) & 7) << 3; }

// pack two floats as bf16 pair into u32 (low = a, high = b)
__device__ __forceinline__ unsigned pk2(float a, float b) {
  union { bf16 h[2]; unsigned u; } c;
  c.h[0] = (bf16)a; c.h[1] = (bf16)b;
  return c.u;
}

// ---------------------------------------------------------------------------
// Dtype detector (unchanged).
// ---------------------------------------------------------------------------
__global__ void k_detect(const void* x, int* flag)
{
  int tid = threadIdx.x;  // 64 threads
  int cnt = 0;
  for (int j = 0; j < 4; j++) {
    int i = (tid * 4 + j) * 2;
    unsigned int u = ((const unsigned short*)x)[i];
    union { unsigned int ui; float f; } c;
    c.ui = u << 16;
    float a = fabsf(c.f);
    if (a >= 1e-4f && a <= 100.f) cnt++;
  }
  for (int m = 1; m < 64; m <<= 1) cnt += __shfl_xor(cnt, m);
  if (tid == 0) *flag = (cnt > 128) ? 1 : 0;
}

// ---------------------------------------------------------------------------
// ck/cv = context @ Wck/Wcv + bias   (4096 rows x 64) -> f32 internal
// ---------------------------------------------------------------------------
__global__ __launch_bounds__(256)
void k_ctx(const int* flagp, const void* ctx, const void* Wck, const void* bck,
           const void* Wcv, const void* bcv, float* __restrict__ ck,
           float* __restrict__ cv)
{
  const int bf = *flagp;
  int rid = blockIdx.x * 4 + (threadIdx.x >> 6);
  int dp = threadIdx.x & 63;
  float a1 = 0.f, a2 = 0.f;
  for (int e = 0; e < 64; e++) {
    float c = ldf(ctx, (size_t)rid * 64 + e, bf);
    a1 += c * ldf(Wck, e * 64 + dp, bf);
    a2 += c * ldf(Wcv, e * 64 + dp, bf);
  }
  ck[rid * 64 + dp] = a1 + ldf(bck, dp, bf);
  cv[rid * 64 + dp] = a2 + ldf(bcv, dp, bf);
}

// ---------------------------------------------------------------------------
// ckq[s][din] = Wcq-row(din) . ck[s] ; cqb[s] = bcq . ck[s]
// Gk[h*64+j][din] = Wk-row(din) . G[h][j] ; gb[h*64+j] = G[h][j] . bk
// ---------------------------------------------------------------------------
__global__ __launch_bounds__(256)
void k_fold(const int* flagp, const float* __restrict__ ck, const void* Wcq,
            const void* bcq, const void* qg, const void* Wk, const void* bk,
            float* __restrict__ ckq, float* __restrict__ cqb,
            float* __restrict__ Gk, float* __restrict__ gb)
{
  const int bf = *flagp;
  int bid = blockIdx.x, tid = threadIdx.x;
  if (bid < 1024) {
    int rid = bid * 4 + (tid >> 6), dp = tid & 63;
    const float* c = ck + (size_t)rid * 64;
    float a = 0.f;
    for (int o = 0; o < 64; o++) a += c[o] * ldf(Wcq, dp * 64 + o, bf);
    ckq[rid * 64 + dp] = a;
    if (dp == 0) {
      float s = 0.f;
      for (int o = 0; o < 64; o++) s += ldf(bcq, o, bf) * c[o];
      cqb[rid] = s;
    }
  } else {
    int i = (bid - 1024) * 256 + tid;    // [0, 32768)
    int row = i >> 6, dIn = i & 63;
    float s = 0.f;
    for (int d = 0; d < 64; d++)
      s += ldf(qg, (size_t)row * 64 + d, bf) * ldf(Wk, dIn * 64 + d, bf);
    Gk[i] = s;
    if (dIn == 0) {
      float t = 0.f;
      for (int d = 0; d < 64; d++)
        t += ldf(qg, (size_t)row * 64 + d, bf) * ldf(bk, d, bf);
      gb[row] = t;
    }
  }
}

// ---------------------------------------------------------------------------
// Attn image prep (re-gridded to 258 blocks):
//   bid 0..127  : ckq f32 -> g_ckqb[bh] ([s][64] swz)        (8 chunks/bh)
//   bid 128..255: cv  f32 -> g_cvtb[bh] ([d][256] swz, T)    (8 chunks/bh)
//   bid 256..257: Gk  f32 -> g_gkb[h]   ([j][64] swz)        (2 halves)
// ---------------------------------------------------------------------------
__global__ __launch_bounds__(256)
void k_prep(const float* __restrict__ ckq, const float* __restrict__ cv,
            const float* __restrict__ Gk, bf16* __restrict__ g_ckqb,
            bf16* __restrict__ g_cvtb, bf16* __restrict__ g_gkb)
{
  const int bid = blockIdx.x, tid = threadIdx.x;
  if (bid < 128) {
    const int bh = bid >> 3, chunk = bid & 7;
    const float* src = ckq + (size_t)bh * 16384;
    bf16* dst = g_ckqb + (size_t)bh * 16384;
    for (int e = tid; e < 2048; e += 256) {
      int idx = chunk * 2048 + e;
      int r = idx >> 6, c = idx & 63;
      dst[r * 64 + (c ^ sw8(r))] = (bf16)src[idx];
    }
  } else if (bid < 256) {
    const int t = bid - 128, bh = t >> 3, chunk = t & 7;
    const float* src = cv + (size_t)bh * 16384;
    bf16* dst = g_cvtb + (size_t)bh * 16384;
    for (int e = tid; e < 2048; e += 256) {
      int idx = chunk * 2048 + e;
      int d = idx >> 8, s = idx & 255;
      dst[d * 256 + (s ^ sw8(d))] = (bf16)src[s * 64 + d];
    }
  } else {
    const int half = bid - 256;
    for (int e = tid; e < 16384; e += 256) {
      int idx = half * 16384 + e;
      int hh = idx >> 12, r = (idx >> 6) & 63, c = idx & 63;
      g_gkb[hh * 4096 + r * 64 + (c ^ sw8(r))] = (bf16)Gk[idx];
    }
  }
}

// ---------------------------------------------------------------------------
// Weight prep: WT[n][k] = (bf16)W[k][n] for Wp (blocks 0..63) and Wo (64..127).
// ---------------------------------------------------------------------------
__global__ __launch_bounds__(256)
void k_wtr(const int* flagp, const void* Wp, const void* Wo,
           bf16* __restrict__ WpT, bf16* __restrict__ WoT)
{
  const int bf = *flagp;
  const int bid = blockIdx.x, tid = threadIdx.x;
  const void* W = (bid < 64) ? Wp : Wo;
  bf16* WT = (bid < 64) ? WpT : WoT;
  const int tb = bid & 63, kb = tb & 7, nb = tb >> 3;
  __shared__ float t[64][65];
  for (int e = tid; e < 4096; e += 256) {
    int k = e >> 6, n = e & 63;
    t[k][n] = ldf(W, (size_t)(kb * 64 + k) * 512 + nb * 64 + n, bf);
  }
  __syncthreads();
  for (int e = tid; e < 4096; e += 256) {
    int n = e >> 6, k = e & 63;
    WT[(size_t)(nb * 64 + n) * 512 + kb * 64 + k] = (bf16)t[k][n];
  }
}

// ---------------------------------------------------------------------------
// MFMA GEMM: out(Mx512) = A(Mx512) @ W(512x512) + bias (unchanged).
// ---------------------------------------------------------------------------
__global__ __launch_bounds__(256)
void k_gemm_mfma(const int* flagp, const void* A, const int amode,
                 const bf16* __restrict__ WT, const void* bias, void* out,
                 const int omode)
{
  __shared__ __attribute__((aligned(16))) bf16 AsB[2][128 * 64];
  __shared__ __attribute__((aligned(16))) bf16 BsB[2][128 * 64];

  const int bf = *flagp;
  const int abf = (amode == 1) || bf;
  const int tid = threadIdx.x;
  const int srow = tid >> 3, schk = tid & 7;

  const int orig = blockIdx.y * 4 + blockIdx.x;
  const int nid = (orig & 7) * 128 + (orig >> 3);
  const int m0 = (nid >> 2) * 128, n0 = (nid & 3) * 128;

  const int lane = tid & 63, wid = tid >> 6;
  const int lo = lane & 15, hi = lane >> 4;
  const int wm = (wid >> 1) * 64, wn = (wid & 1) * 64;

  f32x4 rf[4][2];
  bf16x8 rb[4];
  bf16x8 rw[4];

  auto ldreg = [&](int kt) {
    const int koff = kt * 64 + schk * 8;
#pragma unroll
    for (int i = 0; i < 4; i++) {
      const int row = i * 32 + srow;
      if (abf) {
        rb[i] = *(const bf16x8*)((const bf16*)A + (size_t)(m0 + row) * 512 + koff);
      } else {
        const float* ap = (const float*)A + (size_t)(m0 + row) * 512 + koff;
        rf[i][0] = *(const f32x4*)ap;
        rf[i][1] = *(const f32x4*)(ap + 4);
      }
      rw[i] = *(const bf16x8*)(WT + (size_t)(n0 + row) * 512 + koff);
    }
  };
  auto stlds = [&](bf16* As, bf16* Bs) {
    const int c = schk * 8;
#pragma unroll
    for (int i = 0; i < 4; i++) {
      const int row = i * 32 + srow;
      bf16x8 v;
      if (abf) {
        v = rb[i];
      } else {
#pragma unroll
        for (int j = 0; j < 4; j++) {
          v[j] = (bf16)rf[i][0][j];
          v[4 + j] = (bf16)rf[i][1][j];
        }
      }
      *(bf16x8*)&As[row * 64 + (c ^ sw8(row))] = v;
      *(bf16x8*)&Bs[row * 64 + (c ^ sw8(row))] = rw[i];
    }
  };

  f32x4 acc[4][4];
#pragma unroll
  for (int mt = 0; mt < 4; mt++)
#pragma unroll
    for (int nt = 0; nt < 4; nt++) acc[mt][nt] = f32x4{0.f, 0.f, 0.f, 0.f};

  ldreg(0);
  stlds(AsB[0], BsB[0]);
  __syncthreads();

  int cur = 0;
  for (int kt = 0; kt < 8; kt++) {
    if (kt < 7) ldreg(kt + 1);
    const bf16* Asc = AsB[cur];
    const bf16* Bsc = BsB[cur];
#pragma unroll
    for (int ks = 0; ks < 2; ks++) {
      short8 af[4], bq[4];
#pragma unroll
      for (int mt = 0; mt < 4; mt++) {
        int r = wm + mt * 16 + lo;
        af[mt] = *(const short8*)&Asc[r * 64 + ((ks * 32 + hi * 8) ^ sw8(r))];
      }
#pragma unroll
      for (int nt = 0; nt < 4; nt++) {
        int r = wn + nt * 16 + lo;
        bq[nt] = *(const short8*)&Bsc[r * 64 + ((ks * 32 + hi * 8) ^ sw8(r))];
      }
#pragma unroll
      for (int mt = 0; mt < 4; mt++)
#pragma unroll
        for (int nt = 0; nt < 4; nt++)
          acc[mt][nt] = __builtin_amdgcn_mfma_f32_16x16x32_bf16(
              af[mt], bq[nt], acc[mt][nt], 0, 0, 0);
    }
    if (kt < 7) stlds(AsB[cur ^ 1], BsB[cur ^ 1]);
    __syncthreads();
    cur ^= 1;
  }

#pragma unroll
  for (int nt = 0; nt < 4; nt++) {
    const int col = n0 + wn + nt * 16 + lo;
    const float bj = ldf(bias, col, bf);
#pragma unroll
    for (int mt = 0; mt < 4; mt++)
#pragma unroll
      for (int r = 0; r < 4; r++) {
        const int rowg = m0 + wm + mt * 16 + hi * 4 + r;
        const float v = acc[mt][nt][r] + bj;
        const size_t oi = (size_t)rowg * 512 + col;
        if (omode == 0 || bf) ((bf16*)out)[oi] = (bf16)v;
        else                  ((float*)out)[oi] = v;
      }
  }
}

// ---------------------------------------------------------------------------
// Stage B (MFMA) (unchanged).
// ---------------------------------------------------------------------------
__global__ __launch_bounds__(256, 2)
void k_stageB(const float* __restrict__ Gk, const float* __restrict__ gb,
              const bf16* __restrict__ xm, float* __restrict__ zpart,
              float* __restrict__ lpart)
{
  __shared__ __attribute__((aligned(16))) char smem[8192 + 65536 + 1024];
  bf16* GkB = (bf16*)smem;
  const int tid = threadIdx.x;
  const int bh = blockIdx.y, b = bh >> 3, h = bh & 7;
  const int split = blockIdx.x;

#pragma unroll
  for (int it = 0; it < 2; it++) {
    int idx = tid + it * 256;
    int r = idx >> 3, c0 = (idx & 7) * 8;
    const float* g = Gk + (size_t)(h * 64 + r) * 64 + c0;
    bf16x8 v;
#pragma unroll
    for (int t = 0; t < 8; t++) v[t] = (bf16)g[t];
    *(bf16x8*)&GkB[r * 64 + (c0 ^ sw8(r))] = v;
  }
  __syncthreads();

  const int wid = tid >> 6, lane = tid & 63;
  const int lo = lane & 15, hi = lane >> 4;
  bf16*  Ew  = (bf16*)(smem + 8192 + wid * 16384);
  short* Xts = (short*)(smem + 8192 + wid * 16384 + 8192);

  short8 gk[4][2];
#pragma unroll
  for (int jt = 0; jt < 4; jt++)
#pragma unroll
    for (int ks = 0; ks < 2; ks++) {
      int r = jt * 16 + lo;
      gk[jt][ks] = *(const short8*)&GkB[r * 64 + ((ks * 32 + hi * 8) ^ sw8(r))];
    }
  float gbl[4][4];
#pragma unroll
  for (int jt = 0; jt < 4; jt++)
#pragma unroll
    for (int r = 0; r < 4; r++)
      gbl[jt][r] = gb[h * 64 + jt * 16 + hi * 4 + r];

  f32x4 zacc[4][4];
  float lacc[4][4];
#pragma unroll
  for (int jt = 0; jt < 4; jt++)
#pragma unroll
    for (int q = 0; q < 4; q++) {
      zacc[jt][q] = f32x4{0.f, 0.f, 0.f, 0.f};
      lacc[jt][q] = 0.f;
    }

  const int tokbase = split * 512 + wid * 128;
  for (int t = 0; t < 4; t++) {
    const int t0 = tokbase + t * 32;
    short8 bx[2][2];
#pragma unroll
    for (int tt = 0; tt < 2; tt++)
#pragma unroll
      for (int ks = 0; ks < 2; ks++)
        bx[tt][ks] = *(const short8*)(xm +
            (size_t)(b * 16384 + t0 + tt * 16 + lo) * 512 + h * 64 +
            ks * 32 + hi * 8);
#pragma unroll
    for (int tt = 0; tt < 2; tt++)
#pragma unroll
      for (int ks = 0; ks < 2; ks++)
#pragma unroll
        for (int e = 0; e < 8; e++) {
          int d = ks * 32 + hi * 8 + e;
          int tok = tt * 16 + lo;
          Xts[d * 64 + (tok ^ sw8(d))] = bx[tt][ks][e];
        }
    f32x4 s[4][2];
#pragma unroll
    for (int jt = 0; jt < 4; jt++)
#pragma unroll
      for (int tt = 0; tt < 2; tt++) s[jt][tt] = f32x4{0.f, 0.f, 0.f, 0.f};
#pragma unroll
    for (int ks = 0; ks < 2; ks++)
#pragma unroll
      for (int jt = 0; jt < 4; jt++)
#pragma unroll
        for (int tt = 0; tt < 2; tt++)
          s[jt][tt] = __builtin_amdgcn_mfma_f32_16x16x32_bf16(
              gk[jt][ks], bx[tt][ks], s[jt][tt], 0, 0, 0);
#pragma unroll
    for (int jt = 0; jt < 4; jt++)
#pragma unroll
      for (int tt = 0; tt < 2; tt++)
#pragma unroll
        for (int r = 0; r < 4; r++) {
          int j = jt * 16 + hi * 4 + r;
          int tok = tt * 16 + lo;
          float e = __expf(s[jt][tt][r] + gbl[jt][r]);
          lacc[jt][r] += e;
          Ew[j * 64 + (tok ^ sw8(j))] = (bf16)e;
        }
    short8 ea[4], xb[4];
#pragma unroll
    for (int jt = 0; jt < 4; jt++) {
      int r = jt * 16 + lo;
      ea[jt] = *(const short8*)&Ew[r * 64 + ((hi * 8) ^ sw8(r))];
    }
#pragma unroll
    for (int dt = 0; dt < 4; dt++) {
      int d = dt * 16 + lo;
      xb[dt] = *(const short8*)(Xts + d * 64 + ((hi * 8) ^ sw8(d)));
    }
#pragma unroll
    for (int jt = 0; jt < 4; jt++)
#pragma unroll
      for (int dt = 0; dt < 4; dt++)
        zacc[jt][dt] = __builtin_amdgcn_mfma_f32_16x16x32_bf16(
            ea[jt], xb[dt], zacc[jt][dt], 0, 0, 0);
  }

  float* lred = (float*)(smem + 8192 + 65536);
#pragma unroll
  for (int jt = 0; jt < 4; jt++)
#pragma unroll
    for (int r = 0; r < 4; r++) {
      float v = lacc[jt][r];
      for (int m = 1; m < 16; m <<= 1) v += __shfl_xor(v, m);
      if (lo == 0) lred[wid * 64 + jt * 16 + hi * 4 + r] = v;
    }
  __syncthreads();

  float* zred = (float*)(smem + 8192);
#pragma unroll
  for (int jt = 0; jt < 4; jt++)
#pragma unroll
    for (int dt = 0; dt < 4; dt++)
#pragma unroll
      for (int r = 0; r < 4; r++)
        zred[wid * 4096 + (jt * 16 + hi * 4 + r) * 64 + dt * 16 + lo] =
            zacc[jt][dt][r];
  __syncthreads();

  const size_t pbase = ((size_t)bh * 32 + split) * 4096;
  for (int i = tid; i < 4096; i += 256)
    zpart[pbase + i] =
        zred[i] + zred[4096 + i] + zred[8192 + i] + zred[12288 + i];
  if (tid < 64)
    lpart[((size_t)bh * 32 + split) * 64 + tid] =
        lred[tid] + lred[64 + tid] + lred[128 + tid] + lred[192 + tid];
}

// ---------------------------------------------------------------------------
// Split reduction (parallel): zsum[bh][i] = sum_sp zpart; lsum likewise.
// grid (16 chunks, 16 bh) x 256 threads: one output element per thread.
// ---------------------------------------------------------------------------
__global__ __launch_bounds__(256)
void k_zred(const float* __restrict__ zpart, const float* __restrict__ lpart,
            float* __restrict__ zsum, float* __restrict__ lsumG)
{
  const int bh = blockIdx.y, chunk = blockIdx.x;
  const int i = chunk * 256 + threadIdx.x;
  float s = 0.f;
  for (int sp = 0; sp < 32; sp++)
    s += zpart[((size_t)bh * 32 + sp) * 4096 + i];
  zsum[(size_t)bh * 4096 + i] = s;
  if (chunk == 0 && threadIdx.x < 64) {
    float t = 0.f;
    for (int sp = 0; sp < 32; sp++)
      t += lpart[((size_t)bh * 32 + sp) * 64 + threadIdx.x];
    lsumG[bh * 64 + threadIdx.x] = t;
  }
}

// z^T image: g_ztb[bh][d][j^sw8(d)] = (zsum[j,:]/l_j) @ Wv[:,d] + bv[d]
// grid (64 j, 16 bh) x 64 threads (d).
__global__ __launch_bounds__(64)
void k_znorm2(const int* flagp, const float* __restrict__ zsum,
              const float* __restrict__ lsumG, const void* Wv, const void* bv,
              bf16* __restrict__ g_ztb)
{
  const int bf = *flagp;
  const int j = blockIdx.x, bh = blockIdx.y, d = threadIdx.x;
  __shared__ float zl[64];
  zl[d] = zsum[(size_t)bh * 4096 + j * 64 + d];
  __syncthreads();
  const float inv = 1.f / lsumG[bh * 64 + j];
  float s = 0.f;
#pragma unroll 8
  for (int e = 0; e < 64; e++) s += zl[e] * ldf(Wv, e * 64 + d, bf);
  g_ztb[(size_t)bh * 4096 + d * 64 + (j ^ sw8(d))] =
      (bf16)(s * inv + ldf(bv, d, bf));
}

// ---------------------------------------------------------------------------
// Merged MFMA flash attention, swapped-QK + in-register P transpose (unchanged).
// ---------------------------------------------------------------------------
template <int NCH, int VSTR, int NB>
__device__ __forceinline__ void attn_part2(
    const bf16* __restrict__ Aq, const bf16* __restrict__ BvT,
    const float (&breg)[NB], const short8 (&ax)[2][2],
    int lo, int hi, f32x4 (&accO)[2][4], float (&ltok)[2])
{
#pragma unroll
  for (int ch = 0; ch < NCH; ch++) {
    const int c0 = ch * 32;
    f32x4 s[2][2];  // [ct][rt]
#pragma unroll
    for (int ct = 0; ct < 2; ct++)
#pragma unroll
      for (int rt = 0; rt < 2; rt++) s[ct][rt] = f32x4{0.f, 0.f, 0.f, 0.f};
#pragma unroll
    for (int ks = 0; ks < 2; ks++) {
      short8 aq[2];
#pragma unroll
      for (int ct = 0; ct < 2; ct++) {
        int n = c0 + ct * 16 + lo;
        aq[ct] = *(const short8*)(Aq + n * 64 + ((ks * 32 + hi * 8) ^ sw8(n)));
      }
#pragma unroll
      for (int ct = 0; ct < 2; ct++)
#pragma unroll
        for (int rt = 0; rt < 2; rt++)
          s[ct][rt] = __builtin_amdgcn_mfma_f32_16x16x32_bf16(
              aq[ct], ax[rt][ks], s[ct][rt], 0, 0, 0);
    }
    unsigned w[2][2][2];
#pragma unroll
    for (int ct = 0; ct < 2; ct++) {
      float b[4];
#pragma unroll
      for (int r = 0; r < 4; r++)
        b[r] = __shfl(breg[(c0 + ct * 16) >> 6],
                      ((c0 + ct * 16) & 63) + hi * 4 + r);
#pragma unroll
      for (int rt = 0; rt < 2; rt++) {
        float e0 = __expf(s[ct][rt][0] + b[0]);
        float e1 = __expf(s[ct][rt][1] + b[1]);
        float e2 = __expf(s[ct][rt][2] + b[2]);
        float e3 = __expf(s[ct][rt][3] + b[3]);
        ltok[rt] += e0 + e1 + e2 + e3;
        w[rt][ct][0] = pk2(e0, e1);
        w[rt][ct][1] = pk2(e2, e3);
      }
    }
#pragma unroll
    for (int rt = 0; rt < 2; rt++) {
      const int s0 = lo + 32 * (hi & 1);
      unsigned t00 = __shfl(w[rt][0][0], s0);
      unsigned t10 = __shfl(w[rt][1][0], s0);
      unsigned t01 = __shfl(w[rt][0][1], s0);
      unsigned t11 = __shfl(w[rt][1][1], s0);
      unsigned t20 = __shfl(w[rt][0][0], s0 + 16);
      unsigned t30 = __shfl(w[rt][1][0], s0 + 16);
      unsigned t21 = __shfl(w[rt][0][1], s0 + 16);
      unsigned t31 = __shfl(w[rt][1][1], s0 + 16);
      union { unsigned u[4]; short8 s8; } pa;
      const bool c1 = (hi >> 1) != 0;
      pa.u[0] = c1 ? t10 : t00;
      pa.u[1] = c1 ? t11 : t01;
      pa.u[2] = c1 ? t30 : t20;
      pa.u[3] = c1 ? t31 : t21;
#pragma unroll
      for (int dt = 0; dt < 4; dt++) {
        int d = dt * 16 + lo;
        short8 bv = *(const short8*)(BvT + d * VSTR + ((c0 + hi * 8) ^ sw8(d)));
        accO[rt][dt] = __builtin_amdgcn_mfma_f32_16x16x32_bf16(
            pa.s8, bv, accO[rt][dt], 0, 0, 0);
      }
    }
  }
}

__global__ __launch_bounds__(512, 4)
void k_attn(const int* flagp, const bf16* __restrict__ g_gkb,
            const bf16* __restrict__ g_ztb, const bf16* __restrict__ g_ckqb,
            const bf16* __restrict__ g_cvtb, const float* __restrict__ cqb,
            const float* __restrict__ gb, const bf16* __restrict__ xm,
            const void* smix, bf16* __restrict__ selfmid)
{
  __shared__ __attribute__((aligned(16))) bf16 S[40960];  // exactly 80 KiB
  bf16* GkB  = S;             // [64][64]
  bf16* zTB  = S + 4096;      // [64][64]
  bf16* ckqB = S + 8192;      // [256][64]
  bf16* cvTB = S + 24576;     // [64][256]

  const int tid = threadIdx.x;
  const int bh = blockIdx.y, b = bh >> 3, h = bh & 7;
  const int lane = tid & 63;

  {
    int i = tid;
    *(bf16x8*)&GkB[i * 8] = *(const bf16x8*)&g_gkb[(size_t)h * 4096 + i * 8];
    *(bf16x8*)&zTB[i * 8] = *(const bf16x8*)&g_ztb[(size_t)bh * 4096 + i * 8];
#pragma unroll
    for (int it = 0; it < 4; it++) {
      int j = tid + it * 512;
      *(bf16x8*)&ckqB[j * 8] =
          *(const bf16x8*)&g_ckqb[(size_t)bh * 16384 + j * 8];
      *(bf16x8*)&cvTB[j * 8] =
          *(const bf16x8*)&g_cvtb[(size_t)bh * 16384 + j * 8];
    }
  }
  float creg[4], greg[1];
#pragma unroll
  for (int q = 0; q < 4; q++) creg[q] = cqb[bh * 256 + q * 64 + lane];
  greg[0] = gb[h * 64 + lane];
  __syncthreads();

  const int wid = tid >> 6;
  const int lo = lane & 15, hi = lane >> 4;
  const int m0 = blockIdx.x * 256 + wid * 32;

  short8 ax[2][2];
#pragma unroll
  for (int rt = 0; rt < 2; rt++)
#pragma unroll
    for (int ks = 0; ks < 2; ks++)
      ax[rt][ks] = *(const short8*)(xm +
          (size_t)(b * 16384 + m0 + rt * 16 + lo) * 512 + h * 64 +
          ks * 32 + hi * 8);

  f32x4 accS[2][4], accC[2][4];
  float l1[2] = {0.f, 0.f}, l2[2] = {0.f, 0.f};
#pragma unroll
  for (int rt = 0; rt < 2; rt++)
#pragma unroll
    for (int dt = 0; dt < 4; dt++) {
      accS[rt][dt] = f32x4{0.f, 0.f, 0.f, 0.f};
      accC[rt][dt] = f32x4{0.f, 0.f, 0.f, 0.f};
    }

  attn_part2<2, 64, 1>(GkB, zTB, greg, ax, lo, hi, accS, l1);     // self
  attn_part2<8, 256, 4>(ckqB, cvTB, creg, ax, lo, hi, accC, l2);  // cross

#pragma unroll
  for (int rt = 0; rt < 2; rt++) {
    float a = l1[rt], c = l2[rt];
    a += __shfl_xor(a, 16); a += __shfl_xor(a, 32);
    c += __shfl_xor(c, 16); c += __shfl_xor(c, 32);
    l1[rt] = 1.f / a;
    l2[rt] = 1.f / c;
  }

  const int bf = *flagp;
  const float wmix = 1.f / (1.f + __expf(-ldf(smix, 0, bf)));
#pragma unroll
  for (int rt = 0; rt < 2; rt++)
#pragma unroll
    for (int r = 0; r < 4; r++) {
      const float invS = __shfl(l1[rt], hi * 4 + r);
      const float invC = __shfl(l2[rt], hi * 4 + r);
      int row = m0 + rt * 16 + hi * 4 + r;
      size_t off = (size_t)(b * 16384 + row) * 512 + h * 64;
#pragma unroll
      for (int dt = 0; dt < 4; dt++) {
        float vS = accS[rt][dt][r] * invS;
        float vC = accC[rt][dt][r] * invC;
        selfmid[off + dt * 16 + lo] = (bf16)(wmix * vS + (1.f - wmix) * vC);
      }
    }
}

// ---------------------------------------------------------------------------
extern "C" void kernel_launch(void* const* d_in, const int* in_sizes, int n_in,
                              void* d_out, int out_size, void* d_ws, size_t ws_size,
                              hipStream_t stream)
{
  const void* x    = d_in[0];
  const void* ctx  = d_in[1];
  const void* qg   = d_in[2];
  const void* Wp   = d_in[3];  const void* bp  = d_in[4];
  const void* Wk   = d_in[5];  const void* bk  = d_in[6];
  const void* Wv   = d_in[7];  const void* bv  = d_in[8];
  const void* Wcq  = d_in[9];  const void* bcq = d_in[10];
  const void* Wck  = d_in[11]; const void* bck = d_in[12];
  const void* Wcv  = d_in[13]; const void* bcv = d_in[14];
  const void* smix = d_in[15];
  const void* Wo   = d_in[16]; const void* bo  = d_in[17];

  char* ws = (char*)d_ws;
  int*   flag    = (int*)(ws);                   // 256 B reserved
  float* ck      = (float*)(ws + 256);           // 1,048,576 (dead after k_fold)
  float* cv      = (float*)(ws + 1048832);       // 1,048,576 (f32, -> k_prep)
  float* ckq     = (float*)(ws + 2097408);       // 1,048,576 (f32, -> k_prep)
  float* cqb     = (float*)(ws + 3145984);       // 16,384
  float* Gk      = (float*)(ws + 3162368);       // 131,072
  float* gb      = (float*)(ws + 3293440);       // 2,048 (ends 3295488)
  bf16*  g_cvtb  = (bf16*)(ws + 3295744);        // 512 KiB
  bf16*  g_ckqb  = (bf16*)(ws + 3820032);        // 512 KiB (ends 4344320)
  bf16*  g_gkb   = (bf16*)(ws + 4348160);        // 64 KiB
  bf16*  g_ztb   = (bf16*)(ws + 4413696);        // 128 KiB (ends 4541952)
  bf16*  xm      = (bf16*)(ws + 5396736);        // 33,554,432 (bf16)
  bf16*  selfmid = (bf16*)(ws + 38951168);       // 33,554,432 (bf16)
  // WpT/WoT reuse the ck region (dead after k_fold)
  bf16*  WpT     = (bf16*)(ws + 256);
  bf16*  WoT     = (bf16*)(ws + 256 + 524288);
  // zpart/lpart/zsum/lsumG park in the selfmid region (dead until k_attn)
  float* zpart   = (float*)(ws + 38951168);                  // 8 MB
  float* lpart   = (float*)(ws + 38951168 + 8388608);        // 128 KB
  float* zsum    = (float*)(ws + 38951168 + 8519680);        // 256 KB
  float* lsumG   = (float*)(ws + 38951168 + 8781824);        // 4 KB

  k_detect<<<1, 64, 0, stream>>>(x, flag);

  k_ctx<<<1024, 256, 0, stream>>>(flag, ctx, Wck, bck, Wcv, bcv, ck, cv);
  k_fold<<<1152, 256, 0, stream>>>(flag, ck, Wcq, bcq, qg, Wk, bk,
                                   ckq, cqb, Gk, gb);

  // bf16 pre-swizzled attn images + weight transposes
  k_prep<<<258, 256, 0, stream>>>(ckq, cv, Gk, g_ckqb, g_cvtb, g_gkb);
  k_wtr<<<128, 256, 0, stream>>>(flag, Wp, Wo, WpT, WoT);

  // x_mid (flat (b,n,h*64+d), bf16) = x @ Wp + bp   [MFMA]
  k_gemm_mfma<<<dim3(4, 256), 256, 0, stream>>>(flag, x, 0, WpT, bp, xm, 0);

  // z partials via MFMA split-K over tokens, then parallel reduce + Wv
  k_stageB<<<dim3(32, 16), 256, 0, stream>>>(Gk, gb, xm, zpart, lpart);
  k_zred<<<dim3(16, 16), 256, 0, stream>>>(zpart, lpart, zsum, lsumG);
  k_znorm2<<<dim3(64, 16), 64, 0, stream>>>(flag, zsum, lsumG, Wv, bv, g_ztb);

  // merged MFMA self+cross attention + sigmoid mix -> selfmid
  k_attn<<<dim3(64, 16), 512, 0, stream>>>(flag, g_gkb, g_ztb, g_ckqb, g_cvtb,
                                           cqb, (const float*)gb, xm, smix,
                                           selfmid);

  // out = selfmid @ Wo + bo  (output dtype chosen by flag)   [MFMA]
  k_gemm_mfma<<<dim3(4, 256), 256, 0, stream>>>(flag, selfmid, 1, WoT, bo,
                                                d_out, 1);
}